// Round 1
// baseline (905.856 us; speedup 1.0000x reference)
//
#include <hip/hip_runtime.h>
#include <hip/hip_bf16.h>

// Problem constants: B=1, N=256, C=128, H=4, D=32
#define N 256
#define C 128
#define H 4
#define D 32
#define LN_EPS 1e-5f
#define INFB 1e9f
#define SCALE 0.17677669529663687f  // 1/sqrt(32)

// ---------------------------------------------------------------------------
// K1: transpose + LayerNorm + tri-bias.
// Row r = a*256+b of xn holds LN(x[b, a, :]) (i.e. x_t[a,b,:]).
// tri-bias stored TRANSPOSED: tbt[h*65536 + b*256 + a] = dot(xn_row(a,b), w_bias[h])
// so the attention kernel reads tbt[h][k][j] coalesced over j.
// One wave per row (64 lanes x 2 channels).
// ---------------------------------------------------------------------------
__global__ __launch_bounds__(256) void ln_kernel(
    const float* __restrict__ x, const float* __restrict__ lnw,
    const float* __restrict__ lnb, const float* __restrict__ wbias,
    float* __restrict__ xn, float* __restrict__ tbt)
{
    const int t = threadIdx.x;
    const int wv = t >> 6, lane = t & 63;
    const int r = blockIdx.x * 4 + wv;
    const int a = r >> 8, b = r & 255;        // xn row (a,b) <- x[b, a, :]

    const float2 v = *(const float2*)&x[((size_t)b * N + a) * C + lane * 2];
    float s  = v.x + v.y;
    float ss = v.x * v.x + v.y * v.y;
    #pragma unroll
    for (int o = 32; o; o >>= 1) {
        s  += __shfl_xor(s,  o);
        ss += __shfl_xor(ss, o);
    }
    const float mu  = s * (1.0f / 128.0f);
    const float var = ss * (1.0f / 128.0f) - mu * mu;
    const float rs  = rsqrtf(var + LN_EPS);

    const float2 lw = *(const float2*)&lnw[lane * 2];
    const float2 lb = *(const float2*)&lnb[lane * 2];
    const float y0 = (v.x - mu) * rs * lw.x + lb.x;
    const float y1 = (v.y - mu) * rs * lw.y + lb.y;
    *(float2*)&xn[(size_t)r * C + lane * 2] = make_float2(y0, y1);

    #pragma unroll
    for (int hh = 0; hh < H; ++hh) {
        const float2 wb2 = *(const float2*)&wbias[hh * C + lane * 2];
        float tv = y0 * wb2.x + y1 * wb2.y;
        #pragma unroll
        for (int o = 32; o; o >>= 1) tv += __shfl_xor(tv, o);
        if (lane == 0) tbt[hh * 65536 + b * N + a] = tv;
    }
}

// ---------------------------------------------------------------------------
// K3: fused QKVG projection + attention + gating for one (i, h).
// Thread t owns xn row (i, t): it projects K[t], V[t] (-> LDS) and q[t], g[t]
// (-> registers). Then each thread runs a lane-local online softmax over all
// 256 keys for its own query j = t. No cross-lane softmax traffic at all.
// K/V LDS reads in the score/PV loops are wave-uniform broadcasts.
// og written at final layout: og[(j*256 + i)*128 + h*32 + d].
// ---------------------------------------------------------------------------
__global__ __launch_bounds__(256, 2) void attn_kernel(
    const float* __restrict__ xn, const float* __restrict__ tbt,
    const float* __restrict__ mask,
    const float* __restrict__ wq, const float* __restrict__ wk,
    const float* __restrict__ wv, const float* __restrict__ wg,
    const float* __restrict__ bg, float* __restrict__ og)
{
    const int i = blockIdx.x;
    const int h = blockIdx.y;
    const int t = threadIdx.x;

    __shared__ float Kt[N * D];   // [k][d]  32 KB
    __shared__ float Vt[N * D];   // [k][d]  32 KB

    const float* __restrict__ row = xn + ((size_t)i * N + t) * C;
    const float* __restrict__ wqh = wq + h * D;
    const float* __restrict__ wkh = wk + h * D;
    const float* __restrict__ wvh = wv + h * D;
    const float* __restrict__ wgh = wg + h * D;

    float qk[D], kk[D], vv[D], gg[D];
    #pragma unroll
    for (int d = 0; d < D; ++d) { qk[d] = 0.f; kk[d] = 0.f; vv[d] = 0.f; gg[d] = 0.f; }

    // Fused 4-way projection over C=128 (weight loads are wave-uniform -> s_load)
    #pragma unroll 1
    for (int cq = 0; cq < C / 4; ++cq) {
        const float4 xv4 = *(const float4*)&row[cq * 4];
        const float xs[4] = {xv4.x, xv4.y, xv4.z, xv4.w};
        #pragma unroll
        for (int cc = 0; cc < 4; ++cc) {
            const int c = cq * 4 + cc;
            const float xv = xs[cc];
            #pragma unroll
            for (int dq = 0; dq < D / 4; ++dq) {
                const float4 aq = *(const float4*)&wqh[c * (H * D) + dq * 4];
                const float4 ak = *(const float4*)&wkh[c * (H * D) + dq * 4];
                const float4 av = *(const float4*)&wvh[c * (H * D) + dq * 4];
                const float4 ag = *(const float4*)&wgh[c * (H * D) + dq * 4];
                qk[dq*4+0] += xv * aq.x; qk[dq*4+1] += xv * aq.y;
                qk[dq*4+2] += xv * aq.z; qk[dq*4+3] += xv * aq.w;
                kk[dq*4+0] += xv * ak.x; kk[dq*4+1] += xv * ak.y;
                kk[dq*4+2] += xv * ak.z; kk[dq*4+3] += xv * ak.w;
                vv[dq*4+0] += xv * av.x; vv[dq*4+1] += xv * av.y;
                vv[dq*4+2] += xv * av.z; vv[dq*4+3] += xv * av.w;
                gg[dq*4+0] += xv * ag.x; gg[dq*4+1] += xv * ag.y;
                gg[dq*4+2] += xv * ag.z; gg[dq*4+3] += xv * ag.w;
            }
        }
    }

    #pragma unroll
    for (int dq = 0; dq < D / 4; ++dq) {
        *(float4*)&Kt[t * D + dq * 4] = make_float4(kk[dq*4], kk[dq*4+1], kk[dq*4+2], kk[dq*4+3]);
        *(float4*)&Vt[t * D + dq * 4] = make_float4(vv[dq*4], vv[dq*4+1], vv[dq*4+2], vv[dq*4+3]);
    }
    #pragma unroll
    for (int d = 0; d < D; ++d) qk[d] *= SCALE;
    __syncthreads();

    // Lane-local online softmax over 256 keys, in chunks of 16
    const int j = t;
    float m = -1e30f, l = 0.f;
    float o[D];
    #pragma unroll
    for (int d = 0; d < D; ++d) o[d] = 0.f;

    const float* __restrict__ tbh = tbt + h * 65536;

    #pragma unroll 1
    for (int chunk = 0; chunk < 16; ++chunk) {
        float s[16];
        #pragma unroll
        for (int u = 0; u < 16; ++u) {
            const int k = chunk * 16 + u;
            float acc = 0.f;
            #pragma unroll
            for (int dq = 0; dq < D / 4; ++dq) {
                const float4 kv = *(const float4*)&Kt[k * D + dq * 4];
                acc += qk[dq*4+0]*kv.x + qk[dq*4+1]*kv.y + qk[dq*4+2]*kv.z + qk[dq*4+3]*kv.w;
            }
            const float mb = INFB * (mask[k * N + i] - 1.0f);  // wave-uniform -> scalar
            s[u] = acc + mb + tbh[k * N + j];                  // coalesced over j
        }
        float cm = s[0];
        #pragma unroll
        for (int u = 1; u < 16; ++u) cm = fmaxf(cm, s[u]);
        const float mn = fmaxf(m, cm);
        const float alpha = __expf(m - mn);
        l *= alpha;
        #pragma unroll
        for (int d = 0; d < D; ++d) o[d] *= alpha;
        #pragma unroll
        for (int u = 0; u < 16; ++u) {
            const int k = chunk * 16 + u;
            const float p = __expf(s[u] - mn);
            l += p;
            #pragma unroll
            for (int dq = 0; dq < D / 4; ++dq) {
                const float4 v4 = *(const float4*)&Vt[k * D + dq * 4];
                o[dq*4+0] += p * v4.x; o[dq*4+1] += p * v4.y;
                o[dq*4+2] += p * v4.z; o[dq*4+3] += p * v4.w;
            }
        }
        m = mn;
    }

    const float linv = 1.0f / l;
    const size_t base = ((size_t)j * N + i) * (H * D) + h * D;
    #pragma unroll
    for (int dq = 0; dq < D / 4; ++dq) {
        float4 r4;
        float* rp = &r4.x;
        #pragma unroll
        for (int u = 0; u < 4; ++u) {
            const int d = dq * 4 + u;
            const float gs = 1.0f / (1.0f + __expf(-(gg[d] + bg[h * D + d])));
            rp[u] = o[d] * linv * gs;
        }
        *(float4*)&og[base + dq * 4] = r4;
    }
}

// ---------------------------------------------------------------------------
// K4: output projection out[row, c] = sum_k og[row, k] * wo[c, k] + bo[c]
// og is already in the final (swapaxes-back) row order.
// Block: 64 rows, k split into 2 halves; wo staged k-major in LDS (4-deep max),
// og tile padded (stride 65) to avoid bank conflicts on broadcast reads.
// ---------------------------------------------------------------------------
__global__ __launch_bounds__(256, 2) void outproj_kernel(
    const float* __restrict__ og, const float* __restrict__ wo,
    const float* __restrict__ bo, float* __restrict__ out)
{
    __shared__ float wol[64 * 128];  // [k][c]   32 KB
    __shared__ float ogl[64 * 65];   // [r][k]   16.6 KB (padded)

    const int t = threadIdx.x;
    const int row0 = blockIdx.x * 64;
    const int tc = t & 15, tr = t >> 4;
    const int c0 = tc * 8, r0 = tr * 4;

    float acc[4][8];
    #pragma unroll
    for (int rr = 0; rr < 4; ++rr)
        #pragma unroll
        for (int cc = 0; cc < 8; ++cc) acc[rr][cc] = 0.f;

    #pragma unroll 1
    for (int kh = 0; kh < 2; ++kh) {
        __syncthreads();
        // stage wo[c][kh*64 + k] -> wol[k][c]
        #pragma unroll 1
        for (int n = 0; n < 8; ++n) {
            const int e = n * 256 + t;
            const int kq = e & 15, c = e >> 4;
            const float4 f = *(const float4*)&wo[c * 128 + kh * 64 + kq * 4];
            wol[(kq*4+0) * 128 + c] = f.x;
            wol[(kq*4+1) * 128 + c] = f.y;
            wol[(kq*4+2) * 128 + c] = f.z;
            wol[(kq*4+3) * 128 + c] = f.w;
        }
        // stage og[(row0+r)][kh*64 + k] -> ogl[r][k]
        #pragma unroll 1
        for (int n = 0; n < 4; ++n) {
            const int e = n * 256 + t;
            const int kq = e & 15, r = e >> 4;
            const float4 f = *(const float4*)&og[(size_t)(row0 + r) * 128 + kh * 64 + kq * 4];
            ogl[r * 65 + kq*4+0] = f.x;
            ogl[r * 65 + kq*4+1] = f.y;
            ogl[r * 65 + kq*4+2] = f.z;
            ogl[r * 65 + kq*4+3] = f.w;
        }
        __syncthreads();
        #pragma unroll 1
        for (int k = 0; k < 64; ++k) {
            const float4 w0 = *(const float4*)&wol[k * 128 + c0];
            const float4 w1 = *(const float4*)&wol[k * 128 + c0 + 4];
            #pragma unroll
            for (int rr = 0; rr < 4; ++rr) {
                const float ov = ogl[(r0 + rr) * 65 + k];
                acc[rr][0] += ov * w0.x; acc[rr][1] += ov * w0.y;
                acc[rr][2] += ov * w0.z; acc[rr][3] += ov * w0.w;
                acc[rr][4] += ov * w1.x; acc[rr][5] += ov * w1.y;
                acc[rr][6] += ov * w1.z; acc[rr][7] += ov * w1.w;
            }
        }
    }

    const float4 b0 = *(const float4*)&bo[c0];
    const float4 b1 = *(const float4*)&bo[c0 + 4];
    #pragma unroll
    for (int rr = 0; rr < 4; ++rr) {
        const size_t ro = (size_t)(row0 + r0 + rr) * 128 + c0;
        *(float4*)&out[ro]     = make_float4(acc[rr][0]+b0.x, acc[rr][1]+b0.y,
                                             acc[rr][2]+b0.z, acc[rr][3]+b0.w);
        *(float4*)&out[ro + 4] = make_float4(acc[rr][4]+b1.x, acc[rr][5]+b1.y,
                                             acc[rr][6]+b1.z, acc[rr][7]+b1.w);
    }
}

// ---------------------------------------------------------------------------
extern "C" void kernel_launch(void* const* d_in, const int* in_sizes, int n_in,
                              void* d_out, int out_size, void* d_ws, size_t ws_size,
                              hipStream_t stream) {
    const float* x     = (const float*)d_in[0];
    const float* mask  = (const float*)d_in[1];
    const float* lnw   = (const float*)d_in[2];
    const float* lnb   = (const float*)d_in[3];
    const float* wbias = (const float*)d_in[4];
    const float* wq    = (const float*)d_in[5];
    const float* wk    = (const float*)d_in[6];
    const float* wv    = (const float*)d_in[7];
    const float* wg    = (const float*)d_in[8];
    const float* bg    = (const float*)d_in[9];
    const float* wo    = (const float*)d_in[10];
    const float* bo    = (const float*)d_in[11];
    float* out = (float*)d_out;

    float* xn  = (float*)d_ws;                 // 65536*128 = 8388608 floats
    float* tbt = xn + 8388608;                 // 4*65536   =  262144 floats
    float* og  = tbt + 262144;                 // 65536*128 = 8388608 floats
    // total ws use: ~68.2 MB

    ln_kernel<<<16384, 256, 0, stream>>>(x, lnw, lnb, wbias, xn, tbt);
    attn_kernel<<<dim3(N, H), 256, 0, stream>>>(xn, tbt, mask, wq, wk, wv, wg, bg, og);
    outproj_kernel<<<1024, 256, 0, stream>>>(og, wo, bo, out);
}

// Round 2
// 622.445 us; speedup vs baseline: 1.4553x; 1.4553x over previous
//
#include <hip/hip_runtime.h>

// Problem constants: B=1, N=256, C=128, H=4, D=32
#define N 256
#define C 128
#define H 4
#define D 32
#define LN_EPS 1e-5f
#define INFB 1e9f
#define SCALE 0.17677669529663687f  // 1/sqrt(32)

// Async global->LDS copy, 16 bytes per lane. HW uses wave-uniform LDS base
// (lane 0's pointer) + lane*16; passing each lane's own contiguous pointer
// matches that exactly.
__device__ __forceinline__ void gld_lds16(const float* g, float* l) {
    __builtin_amdgcn_global_load_lds(
        (const __attribute__((address_space(1))) void*)g,
        (__attribute__((address_space(3))) void*)l, 16, 0, 0);
}

// ---------------------------------------------------------------------------
// K1: tri-bias only. Row (a,b): LN(x[b,a,:]) dotted with w_bias[h], stored
// TRANSPOSED tbt[h][b][a] so attention reads tbt[h][k][j] coalesced over j.
// One wave per row (64 lanes x 2 channels). Writes only 1 MB.
// ---------------------------------------------------------------------------
__global__ __launch_bounds__(256) void tb_kernel(
    const float* __restrict__ x, const float* __restrict__ lnw,
    const float* __restrict__ lnb, const float* __restrict__ wbias,
    float* __restrict__ tbt)
{
    const int t = threadIdx.x;
    const int wv = t >> 6, lane = t & 63;
    const int r = blockIdx.x * 4 + wv;
    const int a = r >> 8, b = r & 255;

    const float2 v = *(const float2*)&x[((size_t)b * N + a) * C + lane * 2];
    float s  = v.x + v.y;
    float ss = v.x * v.x + v.y * v.y;
    #pragma unroll
    for (int o = 32; o; o >>= 1) {
        s  += __shfl_xor(s,  o);
        ss += __shfl_xor(ss, o);
    }
    const float mu  = s * (1.0f / 128.0f);
    const float var = ss * (1.0f / 128.0f) - mu * mu;
    const float rs  = rsqrtf(var + LN_EPS);

    const float2 lw = *(const float2*)&lnw[lane * 2];
    const float2 lb = *(const float2*)&lnb[lane * 2];
    const float y0 = (v.x - mu) * rs * lw.x + lb.x;
    const float y1 = (v.y - mu) * rs * lw.y + lb.y;

    #pragma unroll
    for (int hh = 0; hh < H; ++hh) {
        const float2 wb2 = *(const float2*)&wbias[hh * C + lane * 2];
        float tv = y0 * wb2.x + y1 * wb2.y;
        #pragma unroll
        for (int o = 32; o; o >>= 1) tv += __shfl_xor(tv, o);
        if (lane == 0) tbt[hh * (N * N) + b * N + a] = tv;
    }
}

// ---------------------------------------------------------------------------
// K2: K/V projection with inline (per-thread) LayerNorm. Block = (i, h),
// thread t = key row k. Writes kbuf/vbuf[((i*H+h)*N + k)*D + d] so the
// attention kernel can DMA-stream 32-key chunks contiguously.
// ---------------------------------------------------------------------------
__global__ __launch_bounds__(256, 4) void kvproj_kernel(
    const float* __restrict__ x, const float* __restrict__ lnw,
    const float* __restrict__ lnb, const float* __restrict__ wk,
    const float* __restrict__ wv, float* __restrict__ kbuf,
    float* __restrict__ vbuf)
{
    const int bid = blockIdx.x;
    const int i = bid >> 2, h = bid & 3;
    const int t = threadIdx.x;
    const float* __restrict__ xr = x + ((size_t)t * N + i) * C;  // x_t[i, t, :]

    // LN stats (per-thread serial; identical op order in attn kernel)
    float s = 0.f, ss = 0.f;
    #pragma unroll
    for (int cq = 0; cq < C / 4; ++cq) {
        const float4 v = *(const float4*)&xr[cq * 4];
        s  += v.x + v.y + v.z + v.w;
        ss += v.x*v.x + v.y*v.y + v.z*v.z + v.w*v.w;
    }
    const float mu = s * (1.0f / C);
    const float rs = rsqrtf(ss * (1.0f / C) - mu * mu + LN_EPS);

    float kk[D], vv[D];
    #pragma unroll
    for (int d = 0; d < D; ++d) { kk[d] = 0.f; vv[d] = 0.f; }

    #pragma unroll 1
    for (int cq = 0; cq < C / 4; ++cq) {
        const float4 xv = *(const float4*)&xr[cq * 4];
        const float xs[4] = {xv.x, xv.y, xv.z, xv.w};
        #pragma unroll
        for (int cc = 0; cc < 4; ++cc) {
            const int c = cq * 4 + cc;
            const float y = (xs[cc] - mu) * rs * lnw[c] + lnb[c];
            #pragma unroll
            for (int dq = 0; dq < D / 4; ++dq) {
                const float4 a = *(const float4*)&wk[c * (H*D) + h * D + dq * 4];
                const float4 b = *(const float4*)&wv[c * (H*D) + h * D + dq * 4];
                kk[dq*4+0] += y * a.x; kk[dq*4+1] += y * a.y;
                kk[dq*4+2] += y * a.z; kk[dq*4+3] += y * a.w;
                vv[dq*4+0] += y * b.x; vv[dq*4+1] += y * b.y;
                vv[dq*4+2] += y * b.z; vv[dq*4+3] += y * b.w;
            }
        }
    }

    float* __restrict__ kout = kbuf + (((size_t)i * H + h) * N + t) * D;
    float* __restrict__ vout = vbuf + (((size_t)i * H + h) * N + t) * D;
    #pragma unroll
    for (int dq = 0; dq < D / 4; ++dq) {
        *(float4*)&kout[dq*4] = make_float4(kk[dq*4], kk[dq*4+1], kk[dq*4+2], kk[dq*4+3]);
        *(float4*)&vout[dq*4] = make_float4(vv[dq*4], vv[dq*4+1], vv[dq*4+2], vv[dq*4+3]);
    }
}

// ---------------------------------------------------------------------------
// K3: attention for one (i, h). Thread t = query j. Q projected per-thread
// (inline LN); K/V streamed global->LDS via async DMA, 32 keys per chunk,
// double-buffered (17 KB LDS total -> high occupancy). Lane-local online
// softmax; gate projection in the epilogue to keep main-loop VGPRs low.
// ---------------------------------------------------------------------------
__global__ __launch_bounds__(256, 4) void attn_kernel(
    const float* __restrict__ x, const float* __restrict__ lnw,
    const float* __restrict__ lnb, const float* __restrict__ tbt,
    const float* __restrict__ mask, const float* __restrict__ wq,
    const float* __restrict__ wg, const float* __restrict__ bg,
    const float* __restrict__ kbuf, const float* __restrict__ vbuf,
    float* __restrict__ og)
{
    const int bid = blockIdx.x;
    const int i = bid >> 2, h = bid & 3;
    const int t = threadIdx.x;

    __shared__ float Ks[2][32 * D];   // 8 KB
    __shared__ float Vs[2][32 * D];   // 8 KB
    __shared__ float mb[N];           // 1 KB

    // mask bias (visible after first barrier)
    mb[t] = INFB * (mask[(size_t)t * N + i] - 1.0f);

    // kick off chunk 0 DMA; overlaps the Q projection below
    const float* __restrict__ kb = kbuf + ((size_t)i * H + h) * N * D;
    const float* __restrict__ vb = vbuf + ((size_t)i * H + h) * N * D;
    gld_lds16(kb + t * 4, &Ks[0][t * 4]);
    gld_lds16(vb + t * 4, &Vs[0][t * 4]);

    // LN stats for row (i, j=t)  (same op order as kvproj)
    const float* __restrict__ xr = x + ((size_t)t * N + i) * C;
    float s = 0.f, ss = 0.f;
    #pragma unroll
    for (int cq = 0; cq < C / 4; ++cq) {
        const float4 v = *(const float4*)&xr[cq * 4];
        s  += v.x + v.y + v.z + v.w;
        ss += v.x*v.x + v.y*v.y + v.z*v.z + v.w*v.w;
    }
    const float mu = s * (1.0f / C);
    const float rs = rsqrtf(ss * (1.0f / C) - mu * mu + LN_EPS);

    // Q projection (scaled)
    float q[D];
    #pragma unroll
    for (int d = 0; d < D; ++d) q[d] = 0.f;
    #pragma unroll 1
    for (int cq = 0; cq < C / 4; ++cq) {
        const float4 xv = *(const float4*)&xr[cq * 4];
        const float xs[4] = {xv.x, xv.y, xv.z, xv.w};
        #pragma unroll
        for (int cc = 0; cc < 4; ++cc) {
            const int c = cq * 4 + cc;
            const float y = (xs[cc] - mu) * rs * lnw[c] + lnb[c];
            #pragma unroll
            for (int dq = 0; dq < D / 4; ++dq) {
                const float4 a = *(const float4*)&wq[c * (H*D) + h * D + dq * 4];
                q[dq*4+0] += y * a.x; q[dq*4+1] += y * a.y;
                q[dq*4+2] += y * a.z; q[dq*4+3] += y * a.w;
            }
        }
    }
    #pragma unroll
    for (int d = 0; d < D; ++d) q[d] *= SCALE;

    // online softmax over 256 keys, 8 chunks of 32 (two 16-key groups each)
    float m = -1e30f, l = 0.f;
    float o[D];
    #pragma unroll
    for (int d = 0; d < D; ++d) o[d] = 0.f;
    const float* __restrict__ tbh = tbt + h * (N * N);

    #pragma unroll 1
    for (int ch = 0; ch < 8; ++ch) {
        const int p = ch & 1;
        __syncthreads();   // drains this chunk's DMA (vmcnt0 before barrier)
        if (ch < 7) {
            gld_lds16(kb + (ch + 1) * 32 * D + t * 4, &Ks[p ^ 1][t * 4]);
            gld_lds16(vb + (ch + 1) * 32 * D + t * 4, &Vs[p ^ 1][t * 4]);
        }
        #pragma unroll 1
        for (int half = 0; half < 2; ++half) {
            const int k0 = ch * 32 + half * 16;
            float sc[16];
            // issue bias loads first (mb broadcast + coalesced tb), then dots
            #pragma unroll
            for (int u = 0; u < 16; ++u)
                sc[u] = mb[k0 + u] + tbh[(size_t)(k0 + u) * N + t];
            #pragma unroll
            for (int u = 0; u < 16; ++u) {
                const int kl = half * 16 + u;
                float acc = 0.f;
                #pragma unroll
                for (int dq = 0; dq < D / 4; ++dq) {
                    const float4 kv = *(const float4*)&Ks[p][kl * D + dq * 4];
                    acc += q[dq*4+0]*kv.x + q[dq*4+1]*kv.y
                         + q[dq*4+2]*kv.z + q[dq*4+3]*kv.w;
                }
                sc[u] += acc;
            }
            float cm = sc[0];
            #pragma unroll
            for (int u = 1; u < 16; ++u) cm = fmaxf(cm, sc[u]);
            const float mn = fmaxf(m, cm);
            const float alpha = __expf(m - mn);
            l *= alpha;
            #pragma unroll
            for (int d = 0; d < D; ++d) o[d] *= alpha;
            #pragma unroll
            for (int u = 0; u < 16; ++u) {
                const int kl = half * 16 + u;
                const float pe = __expf(sc[u] - mn);
                l += pe;
                #pragma unroll
                for (int dq = 0; dq < D / 4; ++dq) {
                    const float4 v4 = *(const float4*)&Vs[p][kl * D + dq * 4];
                    o[dq*4+0] += pe * v4.x; o[dq*4+1] += pe * v4.y;
                    o[dq*4+2] += pe * v4.z; o[dq*4+3] += pe * v4.w;
                }
            }
            m = mn;
        }
    }

    // epilogue: gate projection (re-reads x row; mu/rs kept in regs)
    const float linv = 1.0f / l;
    float gg[D];
    #pragma unroll
    for (int d = 0; d < D; ++d) gg[d] = 0.f;
    #pragma unroll 1
    for (int cq = 0; cq < C / 4; ++cq) {
        const float4 xv = *(const float4*)&xr[cq * 4];
        const float xs[4] = {xv.x, xv.y, xv.z, xv.w};
        #pragma unroll
        for (int cc = 0; cc < 4; ++cc) {
            const int c = cq * 4 + cc;
            const float y = (xs[cc] - mu) * rs * lnw[c] + lnb[c];
            #pragma unroll
            for (int dq = 0; dq < D / 4; ++dq) {
                const float4 a = *(const float4*)&wg[c * (H*D) + h * D + dq * 4];
                gg[dq*4+0] += y * a.x; gg[dq*4+1] += y * a.y;
                gg[dq*4+2] += y * a.z; gg[dq*4+3] += y * a.w;
            }
        }
    }

    float* __restrict__ ogp = og + (((size_t)t * N + i) * (H * D)) + h * D;
    #pragma unroll
    for (int dq = 0; dq < D / 4; ++dq) {
        float4 r4;
        float* rp = &r4.x;
        #pragma unroll
        for (int u = 0; u < 4; ++u) {
            const int d = dq * 4 + u;
            const float gs = 1.0f / (1.0f + __expf(-(gg[d] + bg[h * D + d])));
            rp[u] = o[d] * linv * gs;
        }
        *(float4*)&ogp[dq * 4] = r4;
    }
}

// ---------------------------------------------------------------------------
// K4: output projection out[row, c] = sum_k og[row, k] * wo[c, k] + bo[c]
// (unchanged from round 1 — not a hot spot)
// ---------------------------------------------------------------------------
__global__ __launch_bounds__(256, 2) void outproj_kernel(
    const float* __restrict__ og, const float* __restrict__ wo,
    const float* __restrict__ bo, float* __restrict__ out)
{
    __shared__ float wol[64 * 128];  // [k][c]
    __shared__ float ogl[64 * 65];   // [r][k] padded

    const int t = threadIdx.x;
    const int row0 = blockIdx.x * 64;
    const int tc = t & 15, tr = t >> 4;
    const int c0 = tc * 8, r0 = tr * 4;

    float acc[4][8];
    #pragma unroll
    for (int rr = 0; rr < 4; ++rr)
        #pragma unroll
        for (int cc = 0; cc < 8; ++cc) acc[rr][cc] = 0.f;

    #pragma unroll 1
    for (int kh = 0; kh < 2; ++kh) {
        __syncthreads();
        #pragma unroll 1
        for (int n = 0; n < 8; ++n) {
            const int e = n * 256 + t;
            const int kq = e & 15, c = e >> 4;
            const float4 f = *(const float4*)&wo[c * 128 + kh * 64 + kq * 4];
            wol[(kq*4+0) * 128 + c] = f.x;
            wol[(kq*4+1) * 128 + c] = f.y;
            wol[(kq*4+2) * 128 + c] = f.z;
            wol[(kq*4+3) * 128 + c] = f.w;
        }
        #pragma unroll 1
        for (int n = 0; n < 4; ++n) {
            const int e = n * 256 + t;
            const int kq = e & 15, r = e >> 4;
            const float4 f = *(const float4*)&og[(size_t)(row0 + r) * 128 + kh * 64 + kq * 4];
            ogl[r * 65 + kq*4+0] = f.x;
            ogl[r * 65 + kq*4+1] = f.y;
            ogl[r * 65 + kq*4+2] = f.z;
            ogl[r * 65 + kq*4+3] = f.w;
        }
        __syncthreads();
        #pragma unroll 1
        for (int k = 0; k < 64; ++k) {
            const float4 w0 = *(const float4*)&wol[k * 128 + c0];
            const float4 w1 = *(const float4*)&wol[k * 128 + c0 + 4];
            #pragma unroll
            for (int rr = 0; rr < 4; ++rr) {
                const float ov = ogl[(r0 + rr) * 65 + k];
                acc[rr][0] += ov * w0.x; acc[rr][1] += ov * w0.y;
                acc[rr][2] += ov * w0.z; acc[rr][3] += ov * w0.w;
                acc[rr][4] += ov * w1.x; acc[rr][5] += ov * w1.y;
                acc[rr][6] += ov * w1.z; acc[rr][7] += ov * w1.w;
            }
        }
    }

    const float4 b0 = *(const float4*)&bo[c0];
    const float4 b1 = *(const float4*)&bo[c0 + 4];
    #pragma unroll
    for (int rr = 0; rr < 4; ++rr) {
        const size_t ro = (size_t)(row0 + r0 + rr) * 128 + c0;
        *(float4*)&out[ro]     = make_float4(acc[rr][0]+b0.x, acc[rr][1]+b0.y,
                                             acc[rr][2]+b0.z, acc[rr][3]+b0.w);
        *(float4*)&out[ro + 4] = make_float4(acc[rr][4]+b1.x, acc[rr][5]+b1.y,
                                             acc[rr][6]+b1.z, acc[rr][7]+b1.w);
    }
}

// ---------------------------------------------------------------------------
extern "C" void kernel_launch(void* const* d_in, const int* in_sizes, int n_in,
                              void* d_out, int out_size, void* d_ws, size_t ws_size,
                              hipStream_t stream) {
    const float* x     = (const float*)d_in[0];
    const float* mask  = (const float*)d_in[1];
    const float* lnw   = (const float*)d_in[2];
    const float* lnb   = (const float*)d_in[3];
    const float* wbias = (const float*)d_in[4];
    const float* wq    = (const float*)d_in[5];
    const float* wk    = (const float*)d_in[6];
    const float* wv    = (const float*)d_in[7];
    const float* wg    = (const float*)d_in[8];
    const float* bg    = (const float*)d_in[9];
    const float* wo    = (const float*)d_in[10];
    const float* bo    = (const float*)d_in[11];
    float* out = (float*)d_out;

    // workspace: tbt (1 MB) + kbuf (33.5) + vbuf (33.5) + og (33.5) = ~102 MB
    float* tbt  = (float*)d_ws;            // 262144
    float* kbuf = tbt  + 262144;           // 8388608
    float* vbuf = kbuf + 8388608;          // 8388608
    float* og   = vbuf + 8388608;          // 8388608

    tb_kernel<<<16384, 256, 0, stream>>>(x, lnw, lnb, wbias, tbt);
    kvproj_kernel<<<1024, 256, 0, stream>>>(x, lnw, lnb, wk, wv, kbuf, vbuf);
    attn_kernel<<<1024, 256, 0, stream>>>(x, lnw, lnb, tbt, mask, wq, wg, bg,
                                          kbuf, vbuf, og);
    outproj_kernel<<<1024, 256, 0, stream>>>(og, wo, bo, out);
}

// Round 3
// 514.463 us; speedup vs baseline: 1.7608x; 1.2099x over previous
//
#include <hip/hip_runtime.h>

// Problem constants: B=1, N=256, C=128, H=4, D=32
#define N 256
#define C 128
#define H 4
#define D 32
#define LN_EPS 1e-5f
#define INFB 1e9f
#define SCALE 0.17677669529663687f  // 1/sqrt(32)

typedef __bf16 bf16x8 __attribute__((ext_vector_type(8)));
typedef float floatx4 __attribute__((ext_vector_type(4)));

__device__ __forceinline__ floatx4 mfma16(bf16x8 a, bf16x8 b, floatx4 c) {
    return __builtin_amdgcn_mfma_f32_16x16x32_bf16(a, b, c, 0, 0, 0);
}

// ---------------------------------------------------------------------------
// K1: tri-bias. tbj[h][j][k] = LN(x_t[j,k,:]) . w_bias[h]  (natural [j][k]
// orientation: the MFMA C-layout reads k = lane&15 contiguous).
// Row r=a*256+b handles (j=a, k=b) from x[b,a,:]. One wave per row.
// ---------------------------------------------------------------------------
__global__ __launch_bounds__(256) void tb_kernel(
    const float* __restrict__ x, const float* __restrict__ lnw,
    const float* __restrict__ lnb, const float* __restrict__ wbias,
    float* __restrict__ tbj)
{
    const int t = threadIdx.x;
    const int wv = t >> 6, lane = t & 63;
    const int r = blockIdx.x * 4 + wv;
    const int a = r >> 8, b = r & 255;

    const float2 v = *(const float2*)&x[((size_t)b * N + a) * C + lane * 2];
    float s  = v.x + v.y;
    float ss = v.x * v.x + v.y * v.y;
    #pragma unroll
    for (int o = 32; o; o >>= 1) {
        s  += __shfl_xor(s,  o);
        ss += __shfl_xor(ss, o);
    }
    const float mu  = s * (1.0f / 128.0f);
    const float var = ss * (1.0f / 128.0f) - mu * mu;
    const float rs  = rsqrtf(var + LN_EPS);

    const float2 lw = *(const float2*)&lnw[lane * 2];
    const float2 lb = *(const float2*)&lnb[lane * 2];
    const float y0 = (v.x - mu) * rs * lw.x + lb.x;
    const float y1 = (v.y - mu) * rs * lw.y + lb.y;

    #pragma unroll
    for (int hh = 0; hh < H; ++hh) {
        const float2 wb2 = *(const float2*)&wbias[hh * C + lane * 2];
        float tv = y0 * wb2.x + y1 * wb2.y;
        #pragma unroll
        for (int o = 32; o; o >>= 1) tv += __shfl_xor(tv, o);
        if (lane == 0) tbj[hh * (N * N) + a * N + b] = tv;  // (j=a, k=b)
    }
}

// ---------------------------------------------------------------------------
// K2: fused LN + QKV projection (fp32) + MFMA flash attention + gate.
// Block = (i, h), 256 threads = 4 waves; wave w owns queries [w*64, w*64+64).
// Thread t projects row t -> q (Qs), k (Ks), v (VT, transposed) in bf16 LDS.
// Scores/PV via mfma_f32_16x16x32_bf16; softmax fp32 in C-layout with
// 16-lane shfl reductions. All LDS strides chosen for <=2-way bank aliasing.
// ---------------------------------------------------------------------------
__global__ __launch_bounds__(256, 2) void attn_kernel(
    const float* __restrict__ x, const float* __restrict__ lnw,
    const float* __restrict__ lnb, const float* __restrict__ tbj,
    const float* __restrict__ mask, const float* __restrict__ wq,
    const float* __restrict__ wk, const float* __restrict__ wv,
    const float* __restrict__ wg, const float* __restrict__ bg,
    float* __restrict__ og)
{
    const int bid = blockIdx.x;
    const int i = bid >> 2, h = bid & 3;
    const int t = threadIdx.x;
    const int w = t >> 6;
    const int lane = t & 63;
    const int ln16 = lane & 15, quad = lane >> 4;

    __shared__ __align__(16) __bf16 Ks[256 * 40];        // 20480 B (stride 40)
    __shared__ __align__(16) __bf16 VT[32 * 264];        // 16896 B (stride 264)
    __shared__ float mb[N];                              // 1024 B
    __shared__ __align__(16) unsigned char QP[4 * 9216]; // Qs(20480) / P / Ot

    mb[t] = INFB * (mask[(size_t)t * N + i] - 1.0f);

    // ---- Phase 1: LN stats + Q/K/V projection for row t ----
    const float* __restrict__ xr = x + ((size_t)t * N + i) * C;
    float s = 0.f, ss = 0.f;
    #pragma unroll
    for (int cq = 0; cq < C / 4; ++cq) {
        const float4 v4 = *(const float4*)&xr[cq * 4];
        s  += v4.x + v4.y + v4.z + v4.w;
        ss += v4.x*v4.x + v4.y*v4.y + v4.z*v4.z + v4.w*v4.w;
    }
    const float mu = s * (1.0f / C);
    const float rs = rsqrtf(ss * (1.0f / C) - mu * mu + LN_EPS);

    float qa[D], ka[D], va[D];
    #pragma unroll
    for (int d = 0; d < D; ++d) { qa[d] = 0.f; ka[d] = 0.f; va[d] = 0.f; }

    #pragma unroll 1
    for (int cq = 0; cq < C / 4; ++cq) {
        const float4 xv = *(const float4*)&xr[cq * 4];
        const float xs[4] = {xv.x, xv.y, xv.z, xv.w};
        #pragma unroll
        for (int cc = 0; cc < 4; ++cc) {
            const int c = cq * 4 + cc;
            const float y = (xs[cc] - mu) * rs * lnw[c] + lnb[c];
            const float* __restrict__ wqc = &wq[c * (H*D) + h * D];
            const float* __restrict__ wkc = &wk[c * (H*D) + h * D];
            const float* __restrict__ wvc = &wv[c * (H*D) + h * D];
            #pragma unroll
            for (int dq = 0; dq < D / 4; ++dq) {
                const float4 aq = *(const float4*)&wqc[dq * 4];
                const float4 ak = *(const float4*)&wkc[dq * 4];
                const float4 av = *(const float4*)&wvc[dq * 4];
                qa[dq*4+0] += y * aq.x; qa[dq*4+1] += y * aq.y;
                qa[dq*4+2] += y * aq.z; qa[dq*4+3] += y * aq.w;
                ka[dq*4+0] += y * ak.x; ka[dq*4+1] += y * ak.y;
                ka[dq*4+2] += y * ak.z; ka[dq*4+3] += y * ak.w;
                va[dq*4+0] += y * av.x; va[dq*4+1] += y * av.y;
                va[dq*4+2] += y * av.z; va[dq*4+3] += y * av.w;
            }
        }
    }

    // stash to LDS in bf16
    __bf16* Qs = (__bf16*)QP;
    #pragma unroll
    for (int dq = 0; dq < 4; ++dq) {
        bf16x8 uq, uk;
        #pragma unroll
        for (int e = 0; e < 8; ++e) {
            uq[e] = (__bf16)(qa[dq*8+e] * SCALE);
            uk[e] = (__bf16)ka[dq*8+e];
        }
        *(bf16x8*)&Qs[t * 40 + dq * 8] = uq;
        *(bf16x8*)&Ks[t * 40 + dq * 8] = uk;
    }
    #pragma unroll
    for (int d = 0; d < D; ++d) VT[d * 264 + t] = (__bf16)va[d];

    __syncthreads();

    // ---- Phase 2: Q A-fragments (wave-local rows) ----
    bf16x8 Qf[4];
    #pragma unroll
    for (int jt = 0; jt < 4; ++jt)
        Qf[jt] = *(const bf16x8*)&Qs[(w*64 + jt*16 + ln16) * 40 + quad * 8];
    __syncthreads();  // everyone done with Qs before P overwrites it

    // ---- Phase 3: flash main loop over 4 chunks of 64 keys ----
    float mrow[4][4], lrow[4][4];
    floatx4 O[4][2];
    const floatx4 z4 = {0.f, 0.f, 0.f, 0.f};
    #pragma unroll
    for (int jt = 0; jt < 4; ++jt) {
        #pragma unroll
        for (int r = 0; r < 4; ++r) { mrow[jt][r] = -1e30f; lrow[jt][r] = 0.f; }
        O[jt][0] = z4; O[jt][1] = z4;
    }

    __bf16* Pw = (__bf16*)(QP + w * 9216);          // 64 rows x 72 bf16
    const float* __restrict__ tbh = tbj + h * (N * N);

    #pragma unroll 1
    for (int c = 0; c < 4; ++c) {
        const int k0 = c * 64;
        bf16x8 Kf[4], Vf[2][2];
        #pragma unroll
        for (int kt = 0; kt < 4; ++kt)
            Kf[kt] = *(const bf16x8*)&Ks[(k0 + kt*16 + ln16) * 40 + quad * 8];
        #pragma unroll
        for (int hf = 0; hf < 2; ++hf)
            #pragma unroll
            for (int dt = 0; dt < 2; ++dt)
                Vf[hf][dt] = *(const bf16x8*)&VT[(dt*16 + ln16) * 264 + k0 + hf*32 + quad * 8];
        float mbv[4];
        #pragma unroll
        for (int kt = 0; kt < 4; ++kt) mbv[kt] = mb[k0 + kt*16 + ln16];

        #pragma unroll 1
        for (int jt = 0; jt < 4; ++jt) {
            const int jrow = w*64 + jt*16 + quad*4;
            // tri-bias loads (issued before MFMAs; no dependency)
            float tbv[4][4];
            #pragma unroll
            for (int kt = 0; kt < 4; ++kt)
                #pragma unroll
                for (int r = 0; r < 4; ++r)
                    tbv[kt][r] = tbh[(size_t)(jrow + r) * N + k0 + kt*16 + ln16];

            floatx4 S[4];
            #pragma unroll
            for (int kt = 0; kt < 4; ++kt) S[kt] = mfma16(Qf[jt], Kf[kt], z4);

            float sc[4][4];
            #pragma unroll
            for (int kt = 0; kt < 4; ++kt)
                #pragma unroll
                for (int r = 0; r < 4; ++r)
                    sc[kt][r] = S[kt][r] + mbv[kt] + tbv[kt][r];

            #pragma unroll
            for (int r = 0; r < 4; ++r) {
                float rm = fmaxf(fmaxf(sc[0][r], sc[1][r]), fmaxf(sc[2][r], sc[3][r]));
                #pragma unroll
                for (int off = 1; off < 16; off <<= 1) rm = fmaxf(rm, __shfl_xor(rm, off));
                const float mo = mrow[jt][r];
                const float mn = fmaxf(mo, rm);
                const float al = __expf(mo - mn);
                mrow[jt][r] = mn;
                float p0 = __expf(sc[0][r] - mn), p1 = __expf(sc[1][r] - mn);
                float p2 = __expf(sc[2][r] - mn), p3 = __expf(sc[3][r] - mn);
                float ls = (p0 + p1) + (p2 + p3);
                #pragma unroll
                for (int off = 1; off < 16; off <<= 1) ls += __shfl_xor(ls, off);
                lrow[jt][r] = lrow[jt][r] * al + ls;
                O[jt][0][r] *= al; O[jt][1][r] *= al;
                __bf16* pr = &Pw[(jt*16 + quad*4 + r) * 72 + ln16];
                pr[0]  = (__bf16)p0; pr[16] = (__bf16)p1;
                pr[32] = (__bf16)p2; pr[48] = (__bf16)p3;
            }
            // PV (wave-local LDS round-trip; DS pipe is in-order per wave)
            const bf16x8 A0 = *(const bf16x8*)&Pw[(jt*16 + ln16) * 72 + quad * 8];
            const bf16x8 A1 = *(const bf16x8*)&Pw[(jt*16 + ln16) * 72 + 32 + quad * 8];
            O[jt][0] = mfma16(A0, Vf[0][0], O[jt][0]);
            O[jt][0] = mfma16(A1, Vf[1][0], O[jt][0]);
            O[jt][1] = mfma16(A0, Vf[0][1], O[jt][1]);
            O[jt][1] = mfma16(A1, Vf[1][1], O[jt][1]);
        }
    }

    // ---- Epilogue: normalize, transpose via LDS, gate, store ----
    float* Ot = (float*)(QP + w * 9216);            // 64 rows x 36 f32
    #pragma unroll
    for (int jt = 0; jt < 4; ++jt)
        #pragma unroll
        for (int r = 0; r < 4; ++r) {
            const float inv = 1.0f / lrow[jt][r];
            Ot[(jt*16 + quad*4 + r) * 36 + ln16]      = O[jt][0][r] * inv;
            Ot[(jt*16 + quad*4 + r) * 36 + 16 + ln16] = O[jt][1][r] * inv;
        }
    __syncthreads();

    // gate projection for row t (fp32, reuses mu/rs)
    float ga[D];
    #pragma unroll
    for (int d = 0; d < D; ++d) ga[d] = 0.f;
    #pragma unroll 1
    for (int cq = 0; cq < C / 4; ++cq) {
        const float4 xv = *(const float4*)&xr[cq * 4];
        const float xs[4] = {xv.x, xv.y, xv.z, xv.w};
        #pragma unroll
        for (int cc = 0; cc < 4; ++cc) {
            const int c = cq * 4 + cc;
            const float y = (xs[cc] - mu) * rs * lnw[c] + lnb[c];
            const float* __restrict__ wgc = &wg[c * (H*D) + h * D];
            #pragma unroll
            for (int dq = 0; dq < D / 4; ++dq) {
                const float4 ag = *(const float4*)&wgc[dq * 4];
                ga[dq*4+0] += y * ag.x; ga[dq*4+1] += y * ag.y;
                ga[dq*4+2] += y * ag.z; ga[dq*4+3] += y * ag.w;
            }
        }
    }

    const float* Otr = (const float*)(QP + w * 9216) + (t & 63) * 36;
    float* __restrict__ ogp = og + ((size_t)t * N + i) * (H * D) + h * D;
    #pragma unroll
    for (int dq = 0; dq < D / 4; ++dq) {
        const float4 o4 = *(const float4*)&Otr[dq * 4];
        float4 r4;
        r4.x = o4.x / (1.0f + __expf(-(ga[dq*4+0] + bg[h*D + dq*4+0])));
        r4.y = o4.y / (1.0f + __expf(-(ga[dq*4+1] + bg[h*D + dq*4+1])));
        r4.z = o4.z / (1.0f + __expf(-(ga[dq*4+2] + bg[h*D + dq*4+2])));
        r4.w = o4.w / (1.0f + __expf(-(ga[dq*4+3] + bg[h*D + dq*4+3])));
        *(float4*)&ogp[dq * 4] = r4;
    }
}

// ---------------------------------------------------------------------------
// K3: output projection out[row, c] = sum_k og[row, k] * wo[c, k] + bo[c]
// ---------------------------------------------------------------------------
__global__ __launch_bounds__(256, 2) void outproj_kernel(
    const float* __restrict__ og, const float* __restrict__ wo,
    const float* __restrict__ bo, float* __restrict__ out)
{
    __shared__ float wol[64 * 128];  // [k][c]
    __shared__ float ogl[64 * 65];   // [r][k] padded

    const int t = threadIdx.x;
    const int row0 = blockIdx.x * 64;
    const int tc = t & 15, tr = t >> 4;
    const int c0 = tc * 8, r0 = tr * 4;

    float acc[4][8];
    #pragma unroll
    for (int rr = 0; rr < 4; ++rr)
        #pragma unroll
        for (int cc = 0; cc < 8; ++cc) acc[rr][cc] = 0.f;

    #pragma unroll 1
    for (int kh = 0; kh < 2; ++kh) {
        __syncthreads();
        #pragma unroll 1
        for (int n = 0; n < 8; ++n) {
            const int e = n * 256 + t;
            const int kq = e & 15, c = e >> 4;
            const float4 f = *(const float4*)&wo[c * 128 + kh * 64 + kq * 4];
            wol[(kq*4+0) * 128 + c] = f.x;
            wol[(kq*4+1) * 128 + c] = f.y;
            wol[(kq*4+2) * 128 + c] = f.z;
            wol[(kq*4+3) * 128 + c] = f.w;
        }
        #pragma unroll 1
        for (int n = 0; n < 4; ++n) {
            const int e = n * 256 + t;
            const int kq = e & 15, r = e >> 4;
            const float4 f = *(const float4*)&og[(size_t)(row0 + r) * 128 + kh * 64 + kq * 4];
            ogl[r * 65 + kq*4+0] = f.x;
            ogl[r * 65 + kq*4+1] = f.y;
            ogl[r * 65 + kq*4+2] = f.z;
            ogl[r * 65 + kq*4+3] = f.w;
        }
        __syncthreads();
        #pragma unroll 1
        for (int k = 0; k < 64; ++k) {
            const float4 w0 = *(const float4*)&wol[k * 128 + c0];
            const float4 w1 = *(const float4*)&wol[k * 128 + c0 + 4];
            #pragma unroll
            for (int rr = 0; rr < 4; ++rr) {
                const float ov = ogl[(r0 + rr) * 65 + k];
                acc[rr][0] += ov * w0.x; acc[rr][1] += ov * w0.y;
                acc[rr][2] += ov * w0.z; acc[rr][3] += ov * w0.w;
                acc[rr][4] += ov * w1.x; acc[rr][5] += ov * w1.y;
                acc[rr][6] += ov * w1.z; acc[rr][7] += ov * w1.w;
            }
        }
    }

    const float4 b0 = *(const float4*)&bo[c0];
    const float4 b1 = *(const float4*)&bo[c0 + 4];
    #pragma unroll
    for (int rr = 0; rr < 4; ++rr) {
        const size_t ro = (size_t)(row0 + r0 + rr) * 128 + c0;
        *(float4*)&out[ro]     = make_float4(acc[rr][0]+b0.x, acc[rr][1]+b0.y,
                                             acc[rr][2]+b0.z, acc[rr][3]+b0.w);
        *(float4*)&out[ro + 4] = make_float4(acc[rr][4]+b1.x, acc[rr][5]+b1.y,
                                             acc[rr][6]+b1.z, acc[rr][7]+b1.w);
    }
}

// ---------------------------------------------------------------------------
extern "C" void kernel_launch(void* const* d_in, const int* in_sizes, int n_in,
                              void* d_out, int out_size, void* d_ws, size_t ws_size,
                              hipStream_t stream) {
    const float* x     = (const float*)d_in[0];
    const float* mask  = (const float*)d_in[1];
    const float* lnw   = (const float*)d_in[2];
    const float* lnb   = (const float*)d_in[3];
    const float* wbias = (const float*)d_in[4];
    const float* wq    = (const float*)d_in[5];
    const float* wk    = (const float*)d_in[6];
    const float* wv    = (const float*)d_in[7];
    const float* wg    = (const float*)d_in[8];
    const float* bg    = (const float*)d_in[9];
    const float* wo    = (const float*)d_in[10];
    const float* bo    = (const float*)d_in[11];
    float* out = (float*)d_out;

    // workspace: tbj (1 MB) + og (33.5 MB)
    float* tbj = (float*)d_ws;             // 262144 floats
    float* og  = tbj + 262144;             // 8388608 floats

    tb_kernel<<<16384, 256, 0, stream>>>(x, lnw, lnb, wbias, tbj);
    attn_kernel<<<1024, 256, 0, stream>>>(x, lnw, lnb, tbj, mask,
                                          wq, wk, wv, wg, bg, og);
    outproj_kernel<<<1024, 256, 0, stream>>>(og, wo, bo, out);
}